// Round 2
// baseline (451.774 us; speedup 1.0000x reference)
//
#include <hip/hip_runtime.h>
#include <hip/hip_bf16.h>
#include <math.h>

#define B_DIM 4
#define C_DIM 256
#define CQK_DIM 32
#define N_POS 4096
#define NPART 4          // j-split partitions

typedef unsigned short u16;
typedef __attribute__((ext_vector_type(8))) short bf16x8;
typedef __attribute__((ext_vector_type(4))) float f32x4;

__device__ __forceinline__ u16 f32_to_bf16_rn(float f) {
    union { float f; unsigned int u; } v; v.f = f;
    unsigned int u = v.u;
    u += 0x7fffu + ((u >> 16) & 1u);
    return (u16)(u >> 16);
}
__device__ __forceinline__ float bf16_to_f32(u16 h) {
    union { unsigned int u; float f; } v; v.u = ((unsigned int)h) << 16;
    return v.f;
}

// ---------------------------------------------------------------------------
// Projection: q = Wq x + bq, k = Wk x + bk (fp32, split to bf16 hi/lo,
// stored [b, n, 32] position-major), v = Wv x + bv (bf16, stored [b, c, n]).
// TI=16 -> 1024 blocks (4/CU) for latency hiding (R1: 512 blocks was 2/CU,
// proj ~113us vs ~20us compute floor).
// ---------------------------------------------------------------------------
__global__ __launch_bounds__(256) void proj_kernel(
    const float* __restrict__ x,
    const float* __restrict__ Wq, const float* __restrict__ bq,
    const float* __restrict__ Wk, const float* __restrict__ bk,
    const float* __restrict__ Wv, const float* __restrict__ bv,
    u16* __restrict__ qhi, u16* __restrict__ qlo,
    u16* __restrict__ khi, u16* __restrict__ klo,
    u16* __restrict__ vbf)
{
    const int TI = 16;
    __shared__ float xs[C_DIM][TI];   // 16 KB
    const int t   = threadIdx.x;
    const int blk = blockIdx.x;       // 0..1023
    const int b   = blk >> 8;
    const int n0  = (blk & 255) * TI;
    const float* xb = x + (size_t)b * C_DIM * N_POS;

    for (int idx = t; idx < C_DIM * TI; idx += 256) {
        int c = idx >> 4, ii = idx & 15;
        xs[c][ii] = xb[(size_t)c * N_POS + n0 + ii];
    }
    __syncthreads();

    // ---- V phase: thread t -> output channel t, 16 positions
    {
        float acc[TI];
        #pragma unroll
        for (int ii = 0; ii < TI; ++ii) acc[ii] = 0.f;
        const float4* wrow = (const float4*)(Wv + t * C_DIM);
        for (int c4 = 0; c4 < C_DIM / 4; ++c4) {
            float4 w4 = wrow[c4];
            #pragma unroll
            for (int u = 0; u < 4; ++u) {
                int c = c4 * 4 + u;
                float w = (u == 0) ? w4.x : (u == 1) ? w4.y : (u == 2) ? w4.z : w4.w;
                const float4* xr = (const float4*)&xs[c][0];
                #pragma unroll
                for (int q8 = 0; q8 < TI / 4; ++q8) {
                    float4 xv = xr[q8];
                    acc[q8 * 4 + 0] += w * xv.x;
                    acc[q8 * 4 + 1] += w * xv.y;
                    acc[q8 * 4 + 2] += w * xv.z;
                    acc[q8 * 4 + 3] += w * xv.w;
                }
            }
        }
        float bias = bv[t];
        __attribute__((aligned(16))) u16 tmp[TI];
        #pragma unroll
        for (int ii = 0; ii < TI; ++ii) tmp[ii] = f32_to_bf16_rn(acc[ii] + bias);
        u16* dst = vbf + ((size_t)b * C_DIM + t) * N_POS + n0;
        *(bf16x8*)(dst)     = *(const bf16x8*)(tmp);
        *(bf16x8*)(dst + 8) = *(const bf16x8*)(tmp + 8);
    }

    // ---- Q/K phase: o = t&63 (0..31 -> q, 32..63 -> k), pos group (t>>6)*4
    {
        int o  = t & 63;
        int ig = (t >> 6) * 4;
        const float* wr = (o < 32) ? (Wq + o * C_DIM) : (Wk + (o - 32) * C_DIM);
        float bias = (o < 32) ? bq[o] : bk[o - 32];
        float acc[4];
        #pragma unroll
        for (int ii = 0; ii < 4; ++ii) acc[ii] = 0.f;
        const float4* wrow = (const float4*)wr;
        for (int c4 = 0; c4 < C_DIM / 4; ++c4) {
            float4 w4 = wrow[c4];
            #pragma unroll
            for (int u = 0; u < 4; ++u) {
                int c = c4 * 4 + u;
                float w = (u == 0) ? w4.x : (u == 1) ? w4.y : (u == 2) ? w4.z : w4.w;
                float4 xa = *(const float4*)&xs[c][ig];
                acc[0] += w * xa.x; acc[1] += w * xa.y;
                acc[2] += w * xa.z; acc[3] += w * xa.w;
            }
        }
        #pragma unroll
        for (int ii = 0; ii < 4; ++ii) {
            float val = acc[ii] + bias;
            u16 hi = f32_to_bf16_rn(val);
            u16 lo = f32_to_bf16_rn(val - bf16_to_f32(hi));
            size_t base = ((size_t)b * N_POS + (n0 + ig + ii)) * CQK_DIM + (o & 31);
            if (o < 32) { qhi[base] = hi; qlo[base] = lo; }
            else        { khi[base] = hi; klo[base] = lo; }
        }
    }
}

// ---------------------------------------------------------------------------
// Flash attention, j-split into NPART partitions (flash-decoding style).
// Each wave: 16 query rows, j-range [p*1024, p*1024+1024). Stores normalized
// partial u_p = O_p / l_p (bf16, [p][b][i][c]) + (m_p, l_p) per row.
// 1024 blocks x 4 waves = 4096 waves = 4 waves/SIMD (R1 had 1 -> latency-bound).
// ---------------------------------------------------------------------------
__global__ __launch_bounds__(256) void flash_kernel(
    const u16* __restrict__ qhi, const u16* __restrict__ qlo,
    const u16* __restrict__ khi, const u16* __restrict__ klo,
    const u16* __restrict__ vbf,
    u16* __restrict__ part, float2* __restrict__ ml)
{
    __shared__ u16 pbuf[4][16 * 72];   // 9216 B; 4-way write conflicts cost ~3K cyc/CU: ignore

    const int t    = threadIdx.x;
    const int wave = t >> 6;
    const int lane = t & 63;
    const int n16  = lane & 15;
    const int quad = lane >> 4;

    // XCD-aware: idx&7 -> xcd; same xcd -> same batch (K/V L2-resident).
    const int idx    = blockIdx.x;          // 0..1023
    const int xcd    = idx & 7;
    const int b      = xcd & 3;
    const int rest   = idx >> 3;            // 0..127
    const int p      = rest & 3;
    const int iouter = rest >> 2;           // 0..31
    const int itile  = (iouter << 1) | (xcd >> 2);   // 0..63
    const int i0     = itile * 64 + wave * 16;

    const u16* qhp = qhi + ((size_t)b * N_POS + i0 + n16) * CQK_DIM + quad * 8;
    const u16* qlp = qlo + ((size_t)b * N_POS + i0 + n16) * CQK_DIM + quad * 8;
    bf16x8 qh = *(const bf16x8*)qhp;
    bf16x8 ql = *(const bf16x8*)qlp;

    f32x4 O[16];
    #pragma unroll
    for (int cb = 0; cb < 16; ++cb) O[cb] = (f32x4){0.f, 0.f, 0.f, 0.f};
    float m_r[4], l_r[4];
    #pragma unroll
    for (int r = 0; r < 4; ++r) { m_r[r] = -INFINITY; l_r[r] = 0.f; }

    const u16* khb = khi + (size_t)b * N_POS * CQK_DIM;
    const u16* klb = klo + (size_t)b * N_POS * CQK_DIM;
    const u16* vb  = vbf + (size_t)b * C_DIM * N_POS;
    u16* pb = pbuf[wave];

    const int jbeg = p * (N_POS / NPART);
    const int jend = jbeg + (N_POS / NPART);
    for (int j0 = jbeg; j0 < jend; j0 += 64) {
        f32x4 s[4];
        #pragma unroll
        for (int jb = 0; jb < 4; ++jb) {
            const int j = j0 + jb * 16 + n16;
            bf16x8 kh = *(const bf16x8*)(khb + (size_t)j * CQK_DIM + quad * 8);
            bf16x8 kl = *(const bf16x8*)(klb + (size_t)j * CQK_DIM + quad * 8);
            f32x4 acc = (f32x4){0.f, 0.f, 0.f, 0.f};
            acc = __builtin_amdgcn_mfma_f32_16x16x32_bf16(qh, kh, acc, 0, 0, 0);
            acc = __builtin_amdgcn_mfma_f32_16x16x32_bf16(qh, kl, acc, 0, 0, 0);
            acc = __builtin_amdgcn_mfma_f32_16x16x32_bf16(ql, kh, acc, 0, 0, 0);
            s[jb] = acc;
        }
        float mt[4], rs[4], alpha[4];
        #pragma unroll
        for (int r = 0; r < 4; ++r)
            mt[r] = fmaxf(fmaxf(s[0][r], s[1][r]), fmaxf(s[2][r], s[3][r]));
        #pragma unroll
        for (int off = 1; off <= 8; off <<= 1) {
            #pragma unroll
            for (int r = 0; r < 4; ++r)
                mt[r] = fmaxf(mt[r], __shfl_xor(mt[r], off, 64));
        }
        #pragma unroll
        for (int r = 0; r < 4; ++r) {
            float mn = fmaxf(m_r[r], mt[r]);
            alpha[r] = __expf(m_r[r] - mn);
            m_r[r] = mn;
            rs[r] = 0.f;
        }
        #pragma unroll
        for (int jb = 0; jb < 4; ++jb) {
            #pragma unroll
            for (int r = 0; r < 4; ++r) {
                float pv = __expf(s[jb][r] - m_r[r]);
                s[jb][r] = pv;
                rs[r] += pv;
            }
        }
        #pragma unroll
        for (int off = 1; off <= 8; off <<= 1) {
            #pragma unroll
            for (int r = 0; r < 4; ++r)
                rs[r] += __shfl_xor(rs[r], off, 64);
        }
        #pragma unroll
        for (int r = 0; r < 4; ++r) l_r[r] = l_r[r] * alpha[r] + rs[r];
        #pragma unroll
        for (int cb = 0; cb < 16; ++cb) {
            #pragma unroll
            for (int r = 0; r < 4; ++r) O[cb][r] *= alpha[r];
        }
        #pragma unroll
        for (int jb = 0; jb < 4; ++jb) {
            #pragma unroll
            for (int r = 0; r < 4; ++r)
                pb[(quad * 4 + r) * 72 + jb * 16 + n16] = f32_to_bf16_rn(s[jb][r]);
        }
        asm volatile("s_waitcnt lgkmcnt(0)" ::: "memory");
        bf16x8 P0 = *(const bf16x8*)(pb + n16 * 72 + quad * 8);
        bf16x8 P1 = *(const bf16x8*)(pb + n16 * 72 + 32 + quad * 8);
        #pragma unroll
        for (int cb = 0; cb < 16; ++cb) {
            const u16* vp = vb + (size_t)(cb * 16 + n16) * N_POS + j0 + quad * 8;
            bf16x8 v0 = *(const bf16x8*)vp;
            bf16x8 v1 = *(const bf16x8*)(vp + 32);
            O[cb] = __builtin_amdgcn_mfma_f32_16x16x32_bf16(P0, v0, O[cb], 0, 0, 0);
            O[cb] = __builtin_amdgcn_mfma_f32_16x16x32_bf16(P1, v1, O[cb], 0, 0, 0);
        }
    }

    // ---- store normalized partial (bf16) + per-row (m, l)
    float inv_l[4];
    #pragma unroll
    for (int r = 0; r < 4; ++r) inv_l[r] = 1.f / l_r[r];
    u16* pbase = part + ((size_t)(p * 4 + b) * N_POS + i0) * C_DIM;
    #pragma unroll
    for (int cb = 0; cb < 16; ++cb) {
        #pragma unroll
        for (int r = 0; r < 4; ++r) {
            pbase[(size_t)(quad * 4 + r) * C_DIM + cb * 16 + n16] =
                f32_to_bf16_rn(O[cb][r] * inv_l[r]);
        }
    }
    if (n16 == 0) {
        #pragma unroll
        for (int r = 0; r < 4; ++r)
            ml[(size_t)(p * 4 + b) * N_POS + i0 + quad * 4 + r] =
                make_float2(m_r[r], l_r[r]);
    }
}

// ---------------------------------------------------------------------------
// Reduce: combine NPART partials, transpose [i][c] -> [c][i] via LDS,
// add residual x, store out. Streaming / HBM-bound (~64 MB).
// ---------------------------------------------------------------------------
__global__ __launch_bounds__(256) void reduce_kernel(
    const u16* __restrict__ part, const float2* __restrict__ ml,
    const float* __restrict__ x, float* __restrict__ out)
{
    const int TJ = 32;
    __shared__ float wgt[NPART][TJ];
    __shared__ float trans[C_DIM][TJ + 1];   // 33.8 KB

    const int t   = threadIdx.x;
    const int blk = blockIdx.x;      // 0..511
    const int b   = blk >> 7;
    const int n0  = (blk & 127) * TJ;

    if (t < TJ) {
        int i = n0 + t;
        float2 a[NPART];
        float mm = -INFINITY;
        #pragma unroll
        for (int p = 0; p < NPART; ++p) {
            a[p] = ml[(size_t)(p * 4 + b) * N_POS + i];
            mm = fmaxf(mm, a[p].x);
        }
        float s = 0.f, w[NPART];
        #pragma unroll
        for (int p = 0; p < NPART; ++p) {
            w[p] = a[p].y * __expf(a[p].x - mm);
            s += w[p];
        }
        float inv = 1.f / s;
        #pragma unroll
        for (int p = 0; p < NPART; ++p) wgt[p][t] = w[p] * inv;
    }
    __syncthreads();

    {
        const int cp = t & 127;       // ushort2 column pair
        const int ih = t >> 7;        // 0/1
        for (int ib = 0; ib < TJ; ib += 2) {
            int i = ib + ih;
            float acc0 = 0.f, acc1 = 0.f;
            #pragma unroll
            for (int p = 0; p < NPART; ++p) {
                const u16* row = part + ((size_t)(p * 4 + b) * N_POS + n0 + i) * C_DIM;
                ushort2 pv = ((const ushort2*)row)[cp];
                float wp = wgt[p][i];
                acc0 += wp * bf16_to_f32(pv.x);
                acc1 += wp * bf16_to_f32(pv.y);
            }
            trans[2 * cp][i]     = acc0;
            trans[2 * cp + 1][i] = acc1;
        }
    }
    __syncthreads();

    {
        const int il = t & 31;
        const int cr = t >> 5;        // 8 c-rows per iteration
        const float* xb = x + (size_t)b * C_DIM * N_POS;
        float* ob       = out + (size_t)b * C_DIM * N_POS;
        for (int cc = 0; cc < 32; ++cc) {
            int c = cc * 8 + cr;
            size_t g = (size_t)c * N_POS + n0 + il;
            ob[g] = trans[c][il] + xb[g];
        }
    }
}

extern "C" void kernel_launch(void* const* d_in, const int* in_sizes, int n_in,
                              void* d_out, int out_size, void* d_ws, size_t ws_size,
                              hipStream_t stream) {
    const float* x  = (const float*)d_in[0];
    const float* Wq = (const float*)d_in[1];
    const float* bq = (const float*)d_in[2];
    const float* Wk = (const float*)d_in[3];
    const float* bk = (const float*)d_in[4];
    const float* Wv = (const float*)d_in[5];
    const float* bv = (const float*)d_in[6];
    float* out = (float*)d_out;

    // ws layout (44.5 MiB):
    //   0..4 MiB   qhi/qlo/khi/klo [B,N,32] bf16 (1 MiB each)
    //   4..12 MiB  vbf [B,C,N] bf16
    //   12..44 MiB part [NPART,B,N,C] bf16 (normalized partials)
    //   44..44.5   ml [NPART,B,N] float2
    char* ws = (char*)d_ws;
    u16*    qhi  = (u16*)(ws);
    u16*    qlo  = (u16*)(ws + (1ull << 20));
    u16*    khi  = (u16*)(ws + (2ull << 20));
    u16*    klo  = (u16*)(ws + (3ull << 20));
    u16*    vbf  = (u16*)(ws + (4ull << 20));
    u16*    part = (u16*)(ws + (12ull << 20));
    float2* mlp  = (float2*)(ws + (44ull << 20));

    hipLaunchKernelGGL(proj_kernel, dim3(1024), dim3(256), 0, stream,
                       x, Wq, bq, Wk, bk, Wv, bv, qhi, qlo, khi, klo, vbf);
    hipLaunchKernelGGL(flash_kernel, dim3(1024), dim3(256), 0, stream,
                       qhi, qlo, khi, klo, vbf, part, mlp);
    hipLaunchKernelGGL(reduce_kernel, dim3(512), dim3(256), 0, stream,
                       part, mlp, x, out);
}